// Round 8
// baseline (604.743 us; speedup 1.0000x reference)
//
#include <hip/hip_runtime.h>
#include <hip/hip_bf16.h>
#include <math.h>

#define NPTS 8192
#define STAT_CNT 262144.0f
#define BN_EPS 1e-5f

typedef __attribute__((__ext_vector_type__(8))) __bf16 bf16x8;
typedef __attribute__((__ext_vector_type__(4))) float f32x4;

// stats region float offsets
#define SD_SUM 0
#define SD_SSQ 4
#define SD_SC 8
#define SD_SH 12
#define SG1_SC 16
#define SG1_SH 144
#define SG2_SC 272
#define SG2_SH 400
#define PG1 528
#define PG2 8720
#define STATS_FLOATS 16912

__device__ __forceinline__ unsigned short f2b(float x){
  unsigned u = __float_as_uint(x);
  return (unsigned short)((u + 0x7FFFu + ((u>>16)&1u)) >> 16);
}
__device__ __forceinline__ float b2f(unsigned short h){
  return __uint_as_float(((unsigned)h)<<16);
}
__device__ __forceinline__ float gelu_f(float x){
  return 0.5f*x*(1.0f + erff(x*0.70710678118654752440f));
}
// XOR-swizzled LDS addressing for [128 rows][256B] bf16 tiles (G4 fix)
__device__ __forceinline__ int swz(int row, int byteInRow){
  return row*256 + (byteInRow ^ ((row&7)<<4));
}
// distance formula shared by both kNN phases: MUST be one inline so phase-1
// and phase-2 roundings are bit-identical (d <= t is exact multiset membership)
__device__ __forceinline__ float dist2f(float qx,float qy,float qz,float qpn,
                                        float x,float y,float z,float w){
  return (qpn + w) - 2.0f*fmaf(qx,x,fmaf(qy,y,qz*z));
}

#define MFMA16(a,b,c) __builtin_amdgcn_mfma_f32_16x16x32_bf16((a),(b),(c),0,0,0)

__device__ __forceinline__ bf16x8 ldsA8(const unsigned short* sA, int row, int k){
  return *(const bf16x8*)((const char*)sA + swz(row, k*2));
}
__device__ __forceinline__ bf16x8 ldW8(const unsigned short* W, int n, int k){
  return *(const bf16x8*)(W + n*128 + k);
}

// wave computes rows [row0,row0+32) x 128 cols; A in swizzled LDS, W bf16 [128][128] row-major
__device__ __forceinline__ void gemm32(f32x4 acc[2][8], const unsigned short* sA,
                                       const unsigned short* W, int row0, int lane){
  int r = lane & 15, g = lane >> 4;
  #pragma unroll
  for (int ks=0; ks<4; ++ks){
    int k = ks*32 + g*8;
    bf16x8 a0 = ldsA8(sA, row0 + r, k);
    bf16x8 a1 = ldsA8(sA, row0 + 16 + r, k);
    #pragma unroll
    for (int nt=0; nt<8; ++nt){
      bf16x8 b = ldW8(W, nt*16 + r, k);
      acc[0][nt] = MFMA16(a0, b, acc[0][nt]);
      acc[1][nt] = MFMA16(a1, b, acc[1][nt]);
    }
  }
}

__global__ __launch_bounds__(256) void k_prep(
    const float* __restrict__ feats, const float* __restrict__ Wq, const float* __restrict__ Wk,
    const float* __restrict__ Wv, const float* __restrict__ Wg1, const float* __restrict__ Wg2,
    unsigned short* __restrict__ wbf, unsigned short* __restrict__ featb, float* __restrict__ stats)
{
  int i = blockIdx.x*256 + threadIdx.x;   // grid covers exactly 2097152
  featb[i] = f2b(feats[i]);
  if (i < 16384){
    wbf[i]        = f2b(Wq[i]);
    wbf[16384+i]  = f2b(Wk[i]);
    wbf[32768+i]  = f2b(Wv[i]);
    wbf[49152+i]  = f2b(Wg1[i]);
    wbf[65536+i]  = f2b(Wg2[i]);
  }
  if (i < STATS_FLOATS) stats[i] = 0.f;
}

// threshold-filter kNN, 4 queries per wave (16 per block) — see R5/R6 notes.
__global__ __launch_bounds__(256) void k_knn4(const float* __restrict__ points, int* __restrict__ idxb){
  __shared__ float2 sxy[2048];
  __shared__ float2 szw[2048];
  __shared__ float svD[16][64];
  __shared__ int   svI[16][64];
  __shared__ int   svC[16];
  int tid = threadIdx.x;
  int wid = tid>>6, lane = tid&63;
  int blk = blockIdx.x;
  int b = (blk*16) >> 13;           // 16 divides 8192: no batch straddle
  const float* cb = points + (size_t)b*NPTS*3;
  int qbase = blk*16 + wid*4;
  float qx[4],qy[4],qz[4],qpn[4],lmin[4],tq[4];
  #pragma unroll
  for (int q=0;q<4;++q){
    const float* qp = points + (size_t)(qbase+q)*3;
    qx[q]=qp[0]; qy[q]=qp[1]; qz[q]=qp[2];
    qpn[q]=fmaf(qz[q],qz[q],fmaf(qy[q],qy[q],qx[q]*qx[q]));
    lmin[q]=3.4e38f;
  }
  if (tid < 16) svC[tid]=0;
  // ---- phase 1: per-query lane minima ----
  for (int tile=0; tile<4; ++tile){
    __syncthreads();
    #pragma unroll
    for (int j=0;j<8;++j){
      int p = j*256 + tid;
      const float* sp = cb + (size_t)(tile*2048+p)*3;
      float x=sp[0], y=sp[1], z=sp[2];
      sxy[p]=make_float2(x,y);
      szw[p]=make_float2(z, fmaf(z,z,fmaf(y,y,x*x)));
    }
    __syncthreads();
    #pragma unroll 2
    for (int s=0;s<32;++s){
      int p = s*64 + lane;
      float2 a = sxy[p], c = szw[p];
      #pragma unroll
      for (int q=0;q<4;++q){
        float d = dist2f(qx[q],qy[q],qz[q],qpn[q], a.x,a.y,c.x,c.y);
        lmin[q] = fminf(lmin[q], d);
      }
    }
  }
  // bitonic sort of 64 lane minima per query; t = 16th smallest
  #pragma unroll
  for (int q=0;q<4;++q){
    float v = lmin[q];
    #pragma unroll
    for (int k=2;k<=64;k<<=1){
      #pragma unroll
      for (int j=k>>1;j>=1;j>>=1){
        float o = __shfl_xor(v, j);
        bool keepmin = ((lane & j)==0) == ((lane & k)==0);
        v = keepmin ? fminf(v,o) : fmaxf(v,o);
      }
    }
    tq[q] = __shfl(v, 15);
  }
  // ---- phase 2: collect survivors ----
  for (int tile=0; tile<4; ++tile){
    __syncthreads();
    #pragma unroll
    for (int j=0;j<8;++j){
      int p = j*256 + tid;
      const float* sp = cb + (size_t)(tile*2048+p)*3;
      float x=sp[0], y=sp[1], z=sp[2];
      sxy[p]=make_float2(x,y);
      szw[p]=make_float2(z, fmaf(z,z,fmaf(y,y,x*x)));
    }
    __syncthreads();
    #pragma unroll 2
    for (int s=0;s<32;++s){
      int p = s*64 + lane;
      float2 a = sxy[p], c = szw[p];
      #pragma unroll
      for (int q=0;q<4;++q){
        float d = dist2f(qx[q],qy[q],qz[q],qpn[q], a.x,a.y,c.x,c.y);
        if (d <= tq[q]){
          int wq = wid*4+q;
          int slot = atomicAdd(&svC[wq], 1);
          if (slot < 64){ svD[wq][slot]=d; svI[wq][slot]=tile*2048+p; }
        }
      }
    }
  }
  __syncthreads();
  // ---- final: exact 16-round extraction per query ----
  #pragma unroll 1
  for (int q=0;q<4;++q){
    int wq = wid*4+q;
    int n = svC[wq]; n = (n>64)?64:n;   // n >= 16 guaranteed
    float td = (lane<n)? svD[wq][lane] : 3.4e38f;
    int   ti = (lane<n)? svI[wq][lane] : 0x7fffffff;
    int myIdx = 0;
    #pragma unroll 1
    for (int r=0;r<16;++r){
      float wd=td; int wi=ti;
      #pragma unroll
      for (int s2=1;s2<64;s2<<=1){
        float od=__shfl_xor(wd,s2); int oi=__shfl_xor(wi,s2);
        bool take = (od<wd)||(od==wd && oi<wi);
        wd=take?od:wd; wi=take?oi:wi;
      }
      if (lane==r) myIdx=wi;
      bool sel = (td==wd)&&(ti==wi);
      td = sel?3.4e38f:td; ti = sel?0x7fffffff:ti;
    }
    if (lane<16) idxb[(size_t)(qbase+q)*16+lane]=myIdx;
  }
}

// thread-per-query BN-d statistics over pos1 = Wd1*(q - nbr) + bd1
__global__ __launch_bounds__(256) void k_dstats(const int* __restrict__ idxb,
    const float* __restrict__ points, const float* __restrict__ Wd1, const float* __restrict__ bd1,
    float* __restrict__ stats){
  __shared__ float sS[6];
  if (threadIdx.x < 6) sS[threadIdx.x]=0.f;
  __syncthreads();
  int qi = blockIdx.x*256 + threadIdx.x;
  int b = qi >> 13;
  const float* qp = points + (size_t)qi*3;
  float qx=qp[0],qy=qp[1],qz=qp[2];
  float w00=Wd1[0],w01=Wd1[1],w02=Wd1[2],w10=Wd1[3],w11=Wd1[4],w12=Wd1[5],w20=Wd1[6],w21=Wd1[7],w22=Wd1[8];
  float b0=bd1[0],b1=bd1[1],b2=bd1[2];
  float s0=0,s1=0,s2=0,q0=0,q1=0,q2=0;
  #pragma unroll
  for (int j=0;j<16;j++){
    int nb = idxb[(size_t)qi*16 + j];
    const float* np_ = points + (size_t)(b*NPTS + nb)*3;
    float dx=qx-np_[0], dy=qy-np_[1], dz=qz-np_[2];
    float t0 = fmaf(dz,w02,fmaf(dy,w01,dx*w00)) + b0;
    float t1 = fmaf(dz,w12,fmaf(dy,w11,dx*w10)) + b1;
    float t2 = fmaf(dz,w22,fmaf(dy,w21,dx*w20)) + b2;
    s0+=t0; s1+=t1; s2+=t2;
    q0=fmaf(t0,t0,q0); q1=fmaf(t1,t1,q1); q2=fmaf(t2,t2,q2);
  }
  atomicAdd(&sS[0],s0); atomicAdd(&sS[1],s1); atomicAdd(&sS[2],s2);
  atomicAdd(&sS[3],q0); atomicAdd(&sS[4],q1); atomicAdd(&sS[5],q2);
  __syncthreads();
  if (threadIdx.x < 3) atomicAdd(&stats[SD_SUM+threadIdx.x], sS[threadIdx.x]);
  else if (threadIdx.x < 6) atomicAdd(&stats[SD_SSQ+threadIdx.x-3], sS[threadIdx.x]);
}

__global__ void k_finalize(float* stats, int sumOff, int ssqOff, const float* __restrict__ gm,
                           const float* __restrict__ bt, int scOff, int shOff, int C){
  int c = blockIdx.x*64 + threadIdx.x;
  if (c >= C) return;
  float m = stats[sumOff+c] * (1.0f/STAT_CNT);
  float v = stats[ssqOff+c] * (1.0f/STAT_CNT) - m*m;
  v = fmaxf(v, 0.0f);
  float rs = rsqrtf(v + BN_EPS);
  float sc = gm[c]*rs;
  stats[scOff+c] = sc;
  stats[shOff+c] = fmaf(-m, sc, bt[c]);
}

// finalize from 32 partial slots of [sum128, ssq128]
__global__ void k_finalizeP(float* stats, int partOff, const float* __restrict__ gm,
                            const float* __restrict__ bt, int scOff, int shOff){
  int c = blockIdx.x*64 + threadIdx.x;   // 2 blocks x 64
  float s=0.f, q=0.f;
  #pragma unroll 4
  for (int p=0;p<32;p++){
    s += stats[partOff + p*256 + c];
    q += stats[partOff + p*256 + 128 + c];
  }
  float m = s * (1.0f/STAT_CNT);
  float v = fmaxf(q*(1.0f/STAT_CNT) - m*m, 0.0f);
  float rs = rsqrtf(v + BN_EPS);
  float sc = gm[c]*rs;
  stats[scOff+c] = sc;
  stats[shOff+c] = fmaf(-m, sc, bt[c]);
}

__global__ __launch_bounds__(256) void k_q(const unsigned short* __restrict__ featb,
    const unsigned short* __restrict__ W, const float* __restrict__ bq, float* __restrict__ qout)
{
  __shared__ __align__(16) unsigned short sA[128*128];
  int tid=threadIdx.x;
  size_t row0=(size_t)blockIdx.x*128;
  for (int t=tid;t<2048;t+=256){
    int row=t>>4,c=t&15;
    uint4 v = *(const uint4*)(featb + (row0+row)*128 + c*8);
    *(uint4*)((char*)sA + swz(row,c*16)) = v;
  }
  __syncthreads();
  int wid=tid>>6, lane=tid&63;
  int r=lane&15, g=lane>>4;
  f32x4 acc[2][8] = {};
  gemm32(acc, sA, W, wid*32, lane);
  #pragma unroll
  for (int nt=0;nt<8;++nt){
    int ch=nt*16+r; float bc=bq[ch];
    #pragma unroll
    for (int mt=0;mt<2;++mt){
      #pragma unroll
      for (int rr=0;rr<4;++rr){
        int row=wid*32+mt*16+g*4+rr;
        qout[(row0+row)*128+ch] = acc[mt][nt][rr] + bc;
      }
    }
  }
}

// 8-wave k_main: 16 rows/wave (acc = 64 VGPR), in-place LDS output staging
// for coalesced 16B stores (R6 fix: 11% occupancy + 1.5x write amplification).
__global__ __launch_bounds__(512, 4) void k_main(
    const float* __restrict__ points, const unsigned short* __restrict__ featb,
    const unsigned short* __restrict__ wbf,
    const float* __restrict__ bk, const float* __restrict__ bv,
    const float* __restrict__ Wd1, const float* __restrict__ bd1,
    const float* __restrict__ Wd2, const float* __restrict__ bd2,
    const int* __restrict__ idxb, const float* __restrict__ qbuf,
    float* __restrict__ stats,
    unsigned short* __restrict__ g1out, unsigned short* __restrict__ valout)
{
  __shared__ __align__(16) unsigned short sA[128*128];
  __shared__ __align__(16) unsigned short sPos[128*128];
  __shared__ float sQ[1024];
  __shared__ int sIdx[128];
  __shared__ float sCtr[24];
  __shared__ float sNbr[384];
  __shared__ float sSum[128];
  __shared__ float sSq[128];
  int tid = threadIdx.x;
  int blk = blockIdx.x;
  int p0 = blk*8;
  int b = p0 >> 13;
  if (tid < 128) sIdx[tid] = idxb[(size_t)p0*16 + tid];
  if (tid >= 128 && tid < 152) sCtr[tid-128] = points[(size_t)p0*3 + tid-128];
  if (tid >= 256 && tid < 384){ sSum[tid-256]=0.f; sSq[tid-256]=0.f; }
  for (int t=tid; t<1024; t+=512) sQ[t] = qbuf[(size_t)p0*128 + t];
  __syncthreads();      // sIdx ready
  if (tid < 128){
    int nb = sIdx[tid];
    const float* pp = points + (size_t)(b*NPTS + nb)*3;
    sNbr[tid*3+0]=pp[0]; sNbr[tid*3+1]=pp[1]; sNbr[tid*3+2]=pp[2];
  }
  for (int t=tid; t<2048; t+=512){
    int row=t>>4, c=t&15;
    int nb = sIdx[row];
    uint4 v = *(const uint4*)(featb + (size_t)(b*NPTS+nb)*128 + c*8);
    *(uint4*)((char*)sA + swz(row, c*16)) = v;
  }
  __syncthreads();      // sA + sNbr ready
  int wid = tid>>6, lane = tid&63;
  int r = lane&15, g = lane>>4;
  int row0 = wid*16;
  f32x4 aK[8] = {};
  f32x4 aV[8] = {};
  {
    const unsigned short* WK = wbf + 16384;
    const unsigned short* WV = wbf + 32768;
    #pragma unroll
    for (int ks=0;ks<4;++ks){
      int k = ks*32 + g*8;
      bf16x8 a0 = ldsA8(sA, row0 + r, k);
      #pragma unroll
      for (int nt=0;nt<8;++nt){
        aK[nt] = MFMA16(a0, ldW8(WK, nt*16 + r, k), aK[nt]);
        aV[nt] = MFMA16(a0, ldW8(WV, nt*16 + r, k), aV[nt]);
      }
    }
  }
  // pos branch: pos1 -> BN-d -> gelu -> Wd2 -> sPos (bf16, swizzled); 4 threads/row
  {
    int row = tid>>2, quarter = tid&3;
    int p = row>>4;
    float dx = sCtr[p*3+0]-sNbr[row*3+0];
    float dy = sCtr[p*3+1]-sNbr[row*3+1];
    float dz = sCtr[p*3+2]-sNbr[row*3+2];
    float scd0=stats[SD_SC+0], scd1=stats[SD_SC+1], scd2=stats[SD_SC+2];
    float shd0=stats[SD_SH+0], shd1=stats[SD_SH+1], shd2=stats[SD_SH+2];
    float t0 = fmaf(dz,Wd1[2],fmaf(dy,Wd1[1],dx*Wd1[0])) + bd1[0];
    float t1 = fmaf(dz,Wd1[5],fmaf(dy,Wd1[4],dx*Wd1[3])) + bd1[1];
    float t2 = fmaf(dz,Wd1[8],fmaf(dy,Wd1[7],dx*Wd1[6])) + bd1[2];
    float g0 = gelu_f(fmaf(t0,scd0,shd0));
    float g1v = gelu_f(fmaf(t1,scd1,shd1));
    float g2v = gelu_f(fmaf(t2,scd2,shd2));
    #pragma unroll
    for (int c8=0;c8<4;++c8){
      int ch0 = quarter*32 + c8*8;
      union { uint4 u; unsigned short s[8]; } o;
      #pragma unroll
      for (int u=0;u<8;u++){
        int ch = ch0+u;
        float pv = fmaf(g2v,Wd2[ch*3+2],fmaf(g1v,Wd2[ch*3+1],g0*Wd2[ch*3+0])) + bd2[ch];
        o.s[u] = f2b(pv);
      }
      *(uint4*)((char*)sPos + swz(row, ch0*2)) = o.u;
    }
  }
  __syncthreads();   // sPos ready; all GEMM reads of sA complete -> sA reusable
  // epilogue: gamma1 = q - key + pos ; value = v + pos ; BN-g1 stats.
  // Stage gamma into sA and val back into the SAME sPos slot just consumed
  // (each (row,ch) slot has exactly one reader==writer: race-free).
  #pragma unroll
  for (int nt=0;nt<8;++nt){
    int ch = nt*16 + r;
    float bkc = bk[ch], bvc = bv[ch];
    float qv = sQ[wid*128 + ch];
    float s_=0.f, qq=0.f;
    #pragma unroll
    for (int rr=0;rr<4;++rr){
      int row = row0 + g*4 + rr;
      int off = swz(row, ch*2);
      float pos = b2f(*(const unsigned short*)((const char*)sPos + off));
      float key = aK[nt][rr] + bkc;
      float val = aV[nt][rr] + bvc + pos;
      float gmv = qv - key + pos;
      s_ += gmv; qq = fmaf(gmv,gmv,qq);
      *(unsigned short*)((char*)sA + off) = f2b(gmv);
      *(unsigned short*)((char*)sPos + off) = f2b(val);
    }
    atomicAdd(&sSum[ch], s_);
    atomicAdd(&sSq[ch], qq);
  }
  __syncthreads();   // staged outputs ready
  {
    size_t rowbase = (size_t)blk*128;
    for (int t=tid; t<2048; t+=512){
      int row=t>>4, c=t&15;
      uint4 gv = *(const uint4*)((const char*)sA + swz(row, c*16));
      uint4 vv = *(const uint4*)((const char*)sPos + swz(row, c*16));
      *(uint4*)(g1out + (rowbase+row)*128 + c*8) = gv;
      *(uint4*)(valout + (rowbase+row)*128 + c*8) = vv;
    }
  }
  if (tid < 128){
    int slot = blk & 31;
    atomicAdd(&stats[PG1 + slot*256 + tid], sSum[tid]);
    atomicAdd(&stats[PG1 + slot*256 + 128 + tid], sSq[tid]);
  }
}

__global__ __launch_bounds__(256) void k_g(
    const unsigned short* __restrict__ gin, const unsigned short* __restrict__ W,
    const float* __restrict__ bias, float* __restrict__ stats, int scOff, int shOff,
    unsigned short* __restrict__ gout, int partOff)
{
  __shared__ __align__(16) unsigned short sA[128*128];
  __shared__ float sSum[128];
  __shared__ float sSq[128];
  int tid = threadIdx.x;
  size_t row0 = (size_t)blockIdx.x*128;
  if (tid<128){ sSum[tid]=0.f; sSq[tid]=0.f; }
  for (int t=tid; t<2048; t+=256){
    int row=t>>4, c=t&15;
    union { uint4 u; unsigned short s[8]; } iv, ov;
    iv.u = *(const uint4*)(gin + (row0+row)*128 + c*8);
    #pragma unroll
    for (int u=0;u<8;u++){
      int ch = c*8+u;
      float x = b2f(iv.s[u]);
      x = gelu_f(fmaf(x, stats[scOff+ch], stats[shOff+ch]));
      ov.s[u] = f2b(x);
    }
    *(uint4*)((char*)sA + swz(row, c*16)) = ov.u;
  }
  __syncthreads();
  int wid=tid>>6, lane=tid&63;
  int r=lane&15, g=lane>>4;
  f32x4 acc[2][8] = {};
  gemm32(acc, sA, W, wid*32, lane);
  #pragma unroll
  for (int nt=0;nt<8;++nt){
    int ch = nt*16+r;
    float bc = bias[ch];
    float s_=0.f, qq=0.f;
    #pragma unroll
    for (int mt=0;mt<2;++mt){
      #pragma unroll
      for (int rr=0;rr<4;++rr){
        int row = wid*32 + mt*16 + g*4 + rr;
        float x = acc[mt][nt][rr] + bc;
        s_ += x; qq = fmaf(x,x,qq);
        gout[(row0+row)*128 + ch] = f2b(x);
      }
    }
    atomicAdd(&sSum[ch], s_); atomicAdd(&sSq[ch], qq);
  }
  __syncthreads();
  if (tid<128){
    int slot = blockIdx.x & 31;
    atomicAdd(&stats[partOff + slot*256 + tid], sSum[tid]);
    atomicAdd(&stats[partOff + slot*256 + 128 + tid], sSq[tid]);
  }
}

__global__ __launch_bounds__(256) void k_out(
    const unsigned short* __restrict__ gin, const unsigned short* __restrict__ W,
    const float* __restrict__ bias, const float* __restrict__ stats, int scOff, int shOff,
    const unsigned short* __restrict__ val, float* __restrict__ outp)
{
  __shared__ __align__(16) unsigned short sA[128*128];
  __shared__ __align__(16) unsigned short sV[128*128];
  int tid=threadIdx.x;
  size_t row0=(size_t)blockIdx.x*128;
  for (int t=tid;t<2048;t+=256){
    int row=t>>4,c=t&15;
    union { uint4 u; unsigned short s[8]; } iv, ov;
    iv.u = *(const uint4*)(gin + (row0+row)*128 + c*8);
    #pragma unroll
    for (int u=0;u<8;u++){
      int ch=c*8+u;
      float x = b2f(iv.s[u]);
      x = gelu_f(fmaf(x, stats[scOff+ch], stats[shOff+ch]));
      ov.s[u]=f2b(x);
    }
    *(uint4*)((char*)sA + swz(row,c*16)) = ov.u;
    uint4 vv = *(const uint4*)(val + (row0+row)*128 + c*8);
    *(uint4*)((char*)sV + swz(row,c*16)) = vv;
  }
  __syncthreads();
  int wid=tid>>6, lane=tid&63;
  int r=lane&15, g=lane>>4;
  f32x4 acc[2][8] = {};
  gemm32(acc, sA, W, wid*32, lane);
  #pragma unroll
  for (int nt=0;nt<8;++nt){
    int ch=nt*16+r; float bc=bias[ch];
    #pragma unroll
    for (int mt=0;mt<2;++mt){
      float g3[4], vv[4];
      #pragma unroll
      for (int rr=0;rr<4;++rr){
        int row=wid*32+mt*16+g*4+rr;
        g3[rr]=acc[mt][nt][rr]+bc;
        vv[rr]=b2f(*(const unsigned short*)((const char*)sV + swz(row, ch*2)));
      }
      float m = fmaxf(fmaxf(g3[0],g3[1]),fmaxf(g3[2],g3[3]));
      m = fmaxf(m, __shfl_xor(m,16));
      m = fmaxf(m, __shfl_xor(m,32));
      float s=0.f, o=0.f;
      #pragma unroll
      for (int rr=0;rr<4;++rr){
        float e = __expf(g3[rr]-m);
        s += e; o = fmaf(e, vv[rr], o);
      }
      s += __shfl_xor(s,16); s += __shfl_xor(s,32);
      o += __shfl_xor(o,16); o += __shfl_xor(o,32);
      if (g==0){
        int p = wid*2+mt;
        outp[((size_t)blockIdx.x*8 + p)*128 + ch] = o/s;
      }
    }
  }
}

extern "C" void kernel_launch(void* const* d_in, const int* in_sizes, int n_in,
                              void* d_out, int out_size, void* d_ws, size_t ws_size,
                              hipStream_t stream)
{
  const float* feats  = (const float*)d_in[0];
  const float* points = (const float*)d_in[1];
  const float* Wq = (const float*)d_in[2];  const float* bq = (const float*)d_in[3];
  const float* Wk = (const float*)d_in[4];  const float* bk = (const float*)d_in[5];
  const float* Wv = (const float*)d_in[6];  const float* bv = (const float*)d_in[7];
  const float* Wd1= (const float*)d_in[8];  const float* bd1= (const float*)d_in[9];
  const float* Wd2= (const float*)d_in[10]; const float* bd2= (const float*)d_in[11];
  const float* Wg1= (const float*)d_in[12]; const float* bg1= (const float*)d_in[13];
  const float* Wg2= (const float*)d_in[14]; const float* bg2= (const float*)d_in[15];
  const float* gd = (const float*)d_in[16]; const float* betad = (const float*)d_in[17];
  const float* gg1= (const float*)d_in[18]; const float* betag1= (const float*)d_in[19];
  const float* gg2= (const float*)d_in[20]; const float* betag2= (const float*)d_in[21];
  float* outp = (float*)d_out;

  char* ws = (char*)d_ws;
  int*    idxb  = (int*)   (ws + 0);                         // 1 MB
  float*  stats = (float*) (ws + 1048576);                   // ~68 KB
  unsigned short* wbf   = (unsigned short*)(ws + 1179648);   // 160 KB
  unsigned short* featb = (unsigned short*)(ws + 1343488);   // 4 MB
  float*  qbuf  = (float*) (ws + 5537792);                   // 8 MB
  unsigned short* g1b = (unsigned short*)(ws + 13926400);    // 64 MB
  unsigned short* vab = (unsigned short*)(ws + 81035264);    // 64 MB
  unsigned short* g2b = (unsigned short*)(ws + 148144128);   // 64 MB

  k_prep<<<dim3(8192),dim3(256),0,stream>>>(feats,Wq,Wk,Wv,Wg1,Wg2,wbf,featb,stats);
  k_knn4<<<dim3(1024),dim3(256),0,stream>>>(points,idxb);
  k_dstats<<<dim3(64),dim3(256),0,stream>>>(idxb,points,Wd1,bd1,stats);
  k_finalize<<<dim3(1),dim3(64),0,stream>>>(stats,SD_SUM,SD_SSQ,gd,betad,SD_SC,SD_SH,3);
  k_q<<<dim3(128),dim3(256),0,stream>>>(featb,wbf,bq,qbuf);
  k_main<<<dim3(2048),dim3(512),0,stream>>>(points,featb,wbf,bk,bv,Wd1,bd1,Wd2,bd2,idxb,qbuf,stats,g1b,vab);
  k_finalizeP<<<dim3(2),dim3(64),0,stream>>>(stats,PG1,gg1,betag1,SG1_SC,SG1_SH);
  k_g<<<dim3(2048),dim3(256),0,stream>>>(g1b,wbf+49152,bg1,stats,SG1_SC,SG1_SH,g2b,PG2);
  k_finalizeP<<<dim3(2),dim3(64),0,stream>>>(stats,PG2,gg2,betag2,SG2_SC,SG2_SH);
  k_out<<<dim3(2048),dim3(256),0,stream>>>(g2b,wbf+65536,bg2,stats,SG2_SC,SG2_SH,vab,outp);
  (void)in_sizes; (void)n_in; (void)out_size; (void)ws_size;
}

// Round 9
// 443.972 us; speedup vs baseline: 1.3621x; 1.3621x over previous
//
#include <hip/hip_runtime.h>
#include <hip/hip_bf16.h>
#include <math.h>

#define NPTS 8192
#define STAT_CNT 262144.0f
#define BN_EPS 1e-5f

typedef __attribute__((__ext_vector_type__(8))) __bf16 bf16x8;
typedef __attribute__((__ext_vector_type__(4))) float f32x4;

// stats region float offsets
#define SD_SUM 0
#define SD_SSQ 4
#define SD_SC 8
#define SD_SH 12
#define SG1_SC 16
#define SG1_SH 144
#define SG2_SC 272
#define SG2_SH 400
#define PG1 528
#define PG2 8720
#define STATS_FLOATS 16912

__device__ __forceinline__ unsigned short f2b(float x){
  unsigned u = __float_as_uint(x);
  return (unsigned short)((u + 0x7FFFu + ((u>>16)&1u)) >> 16);
}
__device__ __forceinline__ float b2f(unsigned short h){
  return __uint_as_float(((unsigned)h)<<16);
}
__device__ __forceinline__ float gelu_f(float x){
  return 0.5f*x*(1.0f + erff(x*0.70710678118654752440f));
}
// XOR-swizzled LDS addressing for [rows][256B] bf16 tiles (G4 fix)
__device__ __forceinline__ int swz(int row, int byteInRow){
  return row*256 + (byteInRow ^ ((row&7)<<4));
}
// distance formula shared by both kNN phases: MUST be one inline so phase-1
// and phase-2 roundings are bit-identical (d <= t is exact multiset membership)
__device__ __forceinline__ float dist2f(float qx,float qy,float qz,float qpn,
                                        float x,float y,float z,float w){
  return (qpn + w) - 2.0f*fmaf(qx,x,fmaf(qy,y,qz*z));
}

#define MFMA16(a,b,c) __builtin_amdgcn_mfma_f32_16x16x32_bf16((a),(b),(c),0,0,0)

__device__ __forceinline__ bf16x8 ldsA8(const unsigned short* sA, int row, int k){
  return *(const bf16x8*)((const char*)sA + swz(row, k*2));
}
__device__ __forceinline__ bf16x8 ldW8(const unsigned short* W, int n, int k){
  return *(const bf16x8*)(W + n*128 + k);
}

// wave computes rows [row0,row0+32) x 128 cols; A in swizzled LDS, W bf16 [128][128] row-major
__device__ __forceinline__ void gemm32(f32x4 acc[2][8], const unsigned short* sA,
                                       const unsigned short* W, int row0, int lane){
  int r = lane & 15, g = lane >> 4;
  #pragma unroll
  for (int ks=0; ks<4; ++ks){
    int k = ks*32 + g*8;
    bf16x8 a0 = ldsA8(sA, row0 + r, k);
    bf16x8 a1 = ldsA8(sA, row0 + 16 + r, k);
    #pragma unroll
    for (int nt=0; nt<8; ++nt){
      bf16x8 b = ldW8(W, nt*16 + r, k);
      acc[0][nt] = MFMA16(a0, b, acc[0][nt]);
      acc[1][nt] = MFMA16(a1, b, acc[1][nt]);
    }
  }
}

__global__ __launch_bounds__(256) void k_prep(
    const float* __restrict__ feats, const float* __restrict__ Wq, const float* __restrict__ Wk,
    const float* __restrict__ Wv, const float* __restrict__ Wg1, const float* __restrict__ Wg2,
    unsigned short* __restrict__ wbf, unsigned short* __restrict__ featb, float* __restrict__ stats)
{
  int i = blockIdx.x*256 + threadIdx.x;   // grid covers exactly 2097152
  featb[i] = f2b(feats[i]);
  if (i < 16384){
    wbf[i]        = f2b(Wq[i]);
    wbf[16384+i]  = f2b(Wk[i]);
    wbf[32768+i]  = f2b(Wv[i]);
    wbf[49152+i]  = f2b(Wg1[i]);
    wbf[65536+i]  = f2b(Wg2[i]);
  }
  if (i < STATS_FLOATS) stats[i] = 0.f;
}

// threshold-filter kNN, 4 queries per wave (16 per block) — see R5/R6 notes.
__global__ __launch_bounds__(256) void k_knn4(const float* __restrict__ points, int* __restrict__ idxb){
  __shared__ float2 sxy[2048];
  __shared__ float2 szw[2048];
  __shared__ float svD[16][64];
  __shared__ int   svI[16][64];
  __shared__ int   svC[16];
  int tid = threadIdx.x;
  int wid = tid>>6, lane = tid&63;
  int blk = blockIdx.x;
  int b = (blk*16) >> 13;           // 16 divides 8192: no batch straddle
  const float* cb = points + (size_t)b*NPTS*3;
  int qbase = blk*16 + wid*4;
  float qx[4],qy[4],qz[4],qpn[4],lmin[4],tq[4];
  #pragma unroll
  for (int q=0;q<4;++q){
    const float* qp = points + (size_t)(qbase+q)*3;
    qx[q]=qp[0]; qy[q]=qp[1]; qz[q]=qp[2];
    qpn[q]=fmaf(qz[q],qz[q],fmaf(qy[q],qy[q],qx[q]*qx[q]));
    lmin[q]=3.4e38f;
  }
  if (tid < 16) svC[tid]=0;
  // ---- phase 1: per-query lane minima ----
  for (int tile=0; tile<4; ++tile){
    __syncthreads();
    #pragma unroll
    for (int j=0;j<8;++j){
      int p = j*256 + tid;
      const float* sp = cb + (size_t)(tile*2048+p)*3;
      float x=sp[0], y=sp[1], z=sp[2];
      sxy[p]=make_float2(x,y);
      szw[p]=make_float2(z, fmaf(z,z,fmaf(y,y,x*x)));
    }
    __syncthreads();
    #pragma unroll 2
    for (int s=0;s<32;++s){
      int p = s*64 + lane;
      float2 a = sxy[p], c = szw[p];
      #pragma unroll
      for (int q=0;q<4;++q){
        float d = dist2f(qx[q],qy[q],qz[q],qpn[q], a.x,a.y,c.x,c.y);
        lmin[q] = fminf(lmin[q], d);
      }
    }
  }
  // bitonic sort of 64 lane minima per query; t = 16th smallest
  #pragma unroll
  for (int q=0;q<4;++q){
    float v = lmin[q];
    #pragma unroll
    for (int k=2;k<=64;k<<=1){
      #pragma unroll
      for (int j=k>>1;j>=1;j>>=1){
        float o = __shfl_xor(v, j);
        bool keepmin = ((lane & j)==0) == ((lane & k)==0);
        v = keepmin ? fminf(v,o) : fmaxf(v,o);
      }
    }
    tq[q] = __shfl(v, 15);
  }
  // ---- phase 2: collect survivors ----
  for (int tile=0; tile<4; ++tile){
    __syncthreads();
    #pragma unroll
    for (int j=0;j<8;++j){
      int p = j*256 + tid;
      const float* sp = cb + (size_t)(tile*2048+p)*3;
      float x=sp[0], y=sp[1], z=sp[2];
      sxy[p]=make_float2(x,y);
      szw[p]=make_float2(z, fmaf(z,z,fmaf(y,y,x*x)));
    }
    __syncthreads();
    #pragma unroll 2
    for (int s=0;s<32;++s){
      int p = s*64 + lane;
      float2 a = sxy[p], c = szw[p];
      #pragma unroll
      for (int q=0;q<4;++q){
        float d = dist2f(qx[q],qy[q],qz[q],qpn[q], a.x,a.y,c.x,c.y);
        if (d <= tq[q]){
          int wq = wid*4+q;
          int slot = atomicAdd(&svC[wq], 1);
          if (slot < 64){ svD[wq][slot]=d; svI[wq][slot]=tile*2048+p; }
        }
      }
    }
  }
  __syncthreads();
  // ---- final: exact 16-round extraction per query ----
  #pragma unroll 1
  for (int q=0;q<4;++q){
    int wq = wid*4+q;
    int n = svC[wq]; n = (n>64)?64:n;   // n >= 16 guaranteed
    float td = (lane<n)? svD[wq][lane] : 3.4e38f;
    int   ti = (lane<n)? svI[wq][lane] : 0x7fffffff;
    int myIdx = 0;
    #pragma unroll 1
    for (int r=0;r<16;++r){
      float wd=td; int wi=ti;
      #pragma unroll
      for (int s2=1;s2<64;s2<<=1){
        float od=__shfl_xor(wd,s2); int oi=__shfl_xor(wi,s2);
        bool take = (od<wd)||(od==wd && oi<wi);
        wd=take?od:wd; wi=take?oi:wi;
      }
      if (lane==r) myIdx=wi;
      bool sel = (td==wd)&&(ti==wi);
      td = sel?3.4e38f:td; ti = sel?0x7fffffff:ti;
    }
    if (lane<16) idxb[(size_t)(qbase+q)*16+lane]=myIdx;
  }
}

// thread-per-query BN-d statistics over pos1 = Wd1*(q - nbr) + bd1
__global__ __launch_bounds__(256) void k_dstats(const int* __restrict__ idxb,
    const float* __restrict__ points, const float* __restrict__ Wd1, const float* __restrict__ bd1,
    float* __restrict__ stats){
  __shared__ float sS[6];
  if (threadIdx.x < 6) sS[threadIdx.x]=0.f;
  __syncthreads();
  int qi = blockIdx.x*256 + threadIdx.x;
  int b = qi >> 13;
  const float* qp = points + (size_t)qi*3;
  float qx=qp[0],qy=qp[1],qz=qp[2];
  float w00=Wd1[0],w01=Wd1[1],w02=Wd1[2],w10=Wd1[3],w11=Wd1[4],w12=Wd1[5],w20=Wd1[6],w21=Wd1[7],w22=Wd1[8];
  float b0=bd1[0],b1=bd1[1],b2=bd1[2];
  float s0=0,s1=0,s2=0,q0=0,q1=0,q2=0;
  #pragma unroll
  for (int j=0;j<16;j++){
    int nb = idxb[(size_t)qi*16 + j];
    const float* np_ = points + (size_t)(b*NPTS + nb)*3;
    float dx=qx-np_[0], dy=qy-np_[1], dz=qz-np_[2];
    float t0 = fmaf(dz,w02,fmaf(dy,w01,dx*w00)) + b0;
    float t1 = fmaf(dz,w12,fmaf(dy,w11,dx*w10)) + b1;
    float t2 = fmaf(dz,w22,fmaf(dy,w21,dx*w20)) + b2;
    s0+=t0; s1+=t1; s2+=t2;
    q0=fmaf(t0,t0,q0); q1=fmaf(t1,t1,q1); q2=fmaf(t2,t2,q2);
  }
  atomicAdd(&sS[0],s0); atomicAdd(&sS[1],s1); atomicAdd(&sS[2],s2);
  atomicAdd(&sS[3],q0); atomicAdd(&sS[4],q1); atomicAdd(&sS[5],q2);
  __syncthreads();
  if (threadIdx.x < 3) atomicAdd(&stats[SD_SUM+threadIdx.x], sS[threadIdx.x]);
  else if (threadIdx.x < 6) atomicAdd(&stats[SD_SSQ+threadIdx.x-3], sS[threadIdx.x]);
}

__global__ void k_finalize(float* stats, int sumOff, int ssqOff, const float* __restrict__ gm,
                           const float* __restrict__ bt, int scOff, int shOff, int C){
  int c = blockIdx.x*64 + threadIdx.x;
  if (c >= C) return;
  float m = stats[sumOff+c] * (1.0f/STAT_CNT);
  float v = stats[ssqOff+c] * (1.0f/STAT_CNT) - m*m;
  v = fmaxf(v, 0.0f);
  float rs = rsqrtf(v + BN_EPS);
  float sc = gm[c]*rs;
  stats[scOff+c] = sc;
  stats[shOff+c] = fmaf(-m, sc, bt[c]);
}

// finalize from 32 partial slots of [sum128, ssq128]
__global__ void k_finalizeP(float* stats, int partOff, const float* __restrict__ gm,
                            const float* __restrict__ bt, int scOff, int shOff){
  int c = blockIdx.x*64 + threadIdx.x;   // 2 blocks x 64
  float s=0.f, q=0.f;
  #pragma unroll 4
  for (int p=0;p<32;p++){
    s += stats[partOff + p*256 + c];
    q += stats[partOff + p*256 + 128 + c];
  }
  float m = s * (1.0f/STAT_CNT);
  float v = fmaxf(q*(1.0f/STAT_CNT) - m*m, 0.0f);
  float rs = rsqrtf(v + BN_EPS);
  float sc = gm[c]*rs;
  stats[scOff+c] = sc;
  stats[shOff+c] = fmaf(-m, sc, bt[c]);
}

// fused Q/K/V projection over contiguous feature rows: 64 rows/block, 4 waves.
// Q stored fp32 (qbuf); K,V stored bf16 with bias folded (kb, vb).
__global__ __launch_bounds__(256) void k_qkv(
    const unsigned short* __restrict__ featb, const unsigned short* __restrict__ wbf,
    const float* __restrict__ bq, const float* __restrict__ bk, const float* __restrict__ bv,
    float* __restrict__ qout, unsigned short* __restrict__ kout, unsigned short* __restrict__ vout)
{
  __shared__ __align__(16) unsigned short sA[64*128];
  int tid = threadIdx.x;
  size_t row0g = (size_t)blockIdx.x*64;
  for (int t=tid; t<1024; t+=256){
    int row=t>>4, cc=t&15;
    uint4 v = *(const uint4*)(featb + (row0g+row)*128 + cc*8);
    *(uint4*)((char*)sA + swz(row, cc*16)) = v;
  }
  __syncthreads();
  int wid=tid>>6, lane=tid&63;
  int r=lane&15, g=lane>>4;
  int row0 = wid*16;
  f32x4 aQ[8]={}, aK[8]={}, aV[8]={};
  const unsigned short* WQ = wbf;
  const unsigned short* WK = wbf+16384;
  const unsigned short* WV = wbf+32768;
  #pragma unroll
  for (int ks=0;ks<4;++ks){
    int k = ks*32 + g*8;
    bf16x8 a0 = ldsA8(sA, row0+r, k);
    #pragma unroll
    for (int nt=0;nt<8;++nt){
      aQ[nt]=MFMA16(a0, ldW8(WQ,nt*16+r,k), aQ[nt]);
      aK[nt]=MFMA16(a0, ldW8(WK,nt*16+r,k), aK[nt]);
      aV[nt]=MFMA16(a0, ldW8(WV,nt*16+r,k), aV[nt]);
    }
  }
  #pragma unroll
  for (int nt=0;nt<8;++nt){
    int ch=nt*16+r;
    float bqc=bq[ch], bkc=bk[ch], bvc=bv[ch];
    #pragma unroll
    for (int rr=0;rr<4;++rr){
      size_t grow = row0g + row0 + g*4 + rr;
      qout[grow*128+ch] = aQ[nt][rr]+bqc;
      kout[grow*128+ch] = f2b(aK[nt][rr]+bkc);
      vout[grow*128+ch] = f2b(aV[nt][rr]+bvc);
    }
  }
}

// streaming fusion: gamma1 = q - gather(K) + pos ; val = gather(V) + pos.
// No GEMM, no LDS tile, no in-loop barriers (R8 lesson: k_main's phase-chain
// was latency-doomed at 2 blocks/CU). 16-lane group per gamma row; 8 ch/thread.
__global__ __launch_bounds__(256) void k_fuse(
    const float* __restrict__ points, const int* __restrict__ idxb,
    const float* __restrict__ qbuf, const unsigned short* __restrict__ kb,
    const unsigned short* __restrict__ vb,
    const float* __restrict__ Wd1, const float* __restrict__ bd1,
    const float* __restrict__ Wd2, const float* __restrict__ bd2,
    float* __restrict__ stats,
    unsigned short* __restrict__ g1out, unsigned short* __restrict__ valout)
{
  __shared__ float sSum[128];
  __shared__ float sSq[128];
  int tid = threadIdx.x, blk = blockIdx.x;
  int slot = tid & 15, jg = tid >> 4;
  int lane = tid & 63;
  int ch0 = slot*8;
  if (tid < 128){ sSum[tid]=0.f; sSq[tid]=0.f; }
  // hoisted per-thread weights (static-indexed arrays -> registers)
  float w2[24], b2v[8];
  #pragma unroll
  for (int u=0;u<8;++u){
    w2[u*3+0]=Wd2[(ch0+u)*3+0];
    w2[u*3+1]=Wd2[(ch0+u)*3+1];
    w2[u*3+2]=Wd2[(ch0+u)*3+2];
    b2v[u]=bd2[ch0+u];
  }
  // this lane computes pos1 component c (lanes 0..2 of each 16-group are read)
  int c = slot & 3; c = (c==3)?2:c;
  float wa  = (c==0)?Wd1[0]:((c==1)?Wd1[3]:Wd1[6]);
  float wb_ = (c==0)?Wd1[1]:((c==1)?Wd1[4]:Wd1[7]);
  float wc  = (c==0)?Wd1[2]:((c==1)?Wd1[5]:Wd1[8]);
  float bc_ = (c==0)?bd1[0]:((c==1)?bd1[1]:bd1[2]);
  float sc_ = (c==0)?stats[SD_SC+0]:((c==1)?stats[SD_SC+1]:stats[SD_SC+2]);
  float sh_ = (c==0)?stats[SD_SH+0]:((c==1)?stats[SD_SH+1]:stats[SD_SH+2]);
  int base = lane & 48;
  float accS[8]={0,0,0,0,0,0,0,0}, accQ[8]={0,0,0,0,0,0,0,0};
  __syncthreads();
  #pragma unroll 2
  for (int i=0;i<8;++i){
    int q = blk*8 + i;
    int b = q >> 13;
    int row = q*16 + jg;
    int nb = idxb[row];
    const float* ctr = points + (size_t)q*3;
    const float* np_ = points + (size_t)(b*NPTS + nb)*3;
    float dx = ctr[0]-np_[0], dy = ctr[1]-np_[1], dz = ctr[2]-np_[2];
    float t = fmaf(dz, wc, fmaf(dy, wb_, dx*wa)) + bc_;
    float tc = gelu_f(fmaf(t, sc_, sh_));
    float g0  = __shfl(tc, base+0);
    float g1v = __shfl(tc, base+1);
    float g2v = __shfl(tc, base+2);
    size_t kvoff = ((size_t)(b*NPTS + nb))*128 + ch0;
    union { uint4 u; unsigned short s[8]; } K, V, G, Vo;
    K.u = *(const uint4*)(kb + kvoff);
    V.u = *(const uint4*)(vb + kvoff);
    float4 q0 = *(const float4*)(qbuf + (size_t)q*128 + ch0);
    float4 q1 = *(const float4*)(qbuf + (size_t)q*128 + ch0 + 4);
    float qv[8] = {q0.x,q0.y,q0.z,q0.w,q1.x,q1.y,q1.z,q1.w};
    #pragma unroll
    for (int u=0;u<8;++u){
      float pos = fmaf(g2v, w2[u*3+2], fmaf(g1v, w2[u*3+1], g0*w2[u*3+0])) + b2v[u];
      float key = b2f(K.s[u]);
      float val = b2f(V.s[u]) + pos;
      float gmv = qv[u] - key + pos;
      accS[u] += gmv; accQ[u] = fmaf(gmv,gmv,accQ[u]);
      G.s[u] = f2b(gmv); Vo.s[u] = f2b(val);
    }
    *(uint4*)(g1out + (size_t)row*128 + ch0) = G.u;
    *(uint4*)(valout + (size_t)row*128 + ch0) = Vo.u;
  }
  #pragma unroll
  for (int u=0;u<8;++u){
    atomicAdd(&sSum[ch0+u], accS[u]);
    atomicAdd(&sSq[ch0+u], accQ[u]);
  }
  __syncthreads();
  if (tid < 128){
    int ps = blk & 31;
    atomicAdd(&stats[PG1 + ps*256 + tid], sSum[tid]);
    atomicAdd(&stats[PG1 + ps*256 + 128 + tid], sSq[tid]);
  }
}

__global__ __launch_bounds__(256) void k_g(
    const unsigned short* __restrict__ gin, const unsigned short* __restrict__ W,
    const float* __restrict__ bias, float* __restrict__ stats, int scOff, int shOff,
    unsigned short* __restrict__ gout, int partOff)
{
  __shared__ __align__(16) unsigned short sA[128*128];
  __shared__ float sSum[128];
  __shared__ float sSq[128];
  int tid = threadIdx.x;
  size_t row0 = (size_t)blockIdx.x*128;
  if (tid<128){ sSum[tid]=0.f; sSq[tid]=0.f; }
  for (int t=tid; t<2048; t+=256){
    int row=t>>4, c=t&15;
    union { uint4 u; unsigned short s[8]; } iv, ov;
    iv.u = *(const uint4*)(gin + (row0+row)*128 + c*8);
    #pragma unroll
    for (int u=0;u<8;u++){
      int ch = c*8+u;
      float x = b2f(iv.s[u]);
      x = gelu_f(fmaf(x, stats[scOff+ch], stats[shOff+ch]));
      ov.s[u] = f2b(x);
    }
    *(uint4*)((char*)sA + swz(row, c*16)) = ov.u;
  }
  __syncthreads();
  int wid=tid>>6, lane=tid&63;
  int r=lane&15, g=lane>>4;
  f32x4 acc[2][8] = {};
  gemm32(acc, sA, W, wid*32, lane);
  #pragma unroll
  for (int nt=0;nt<8;++nt){
    int ch = nt*16+r;
    float bc = bias[ch];
    float s_=0.f, qq=0.f;
    #pragma unroll
    for (int mt=0;mt<2;++mt){
      #pragma unroll
      for (int rr=0;rr<4;++rr){
        int row = wid*32 + mt*16 + g*4 + rr;
        float x = acc[mt][nt][rr] + bc;
        s_ += x; qq = fmaf(x,x,qq);
        gout[(row0+row)*128 + ch] = f2b(x);
      }
    }
    atomicAdd(&sSum[ch], s_); atomicAdd(&sSq[ch], qq);
  }
  __syncthreads();
  if (tid<128){
    int slot = blockIdx.x & 31;
    atomicAdd(&stats[partOff + slot*256 + tid], sSum[tid]);
    atomicAdd(&stats[partOff + slot*256 + 128 + tid], sSq[tid]);
  }
}

__global__ __launch_bounds__(256) void k_out(
    const unsigned short* __restrict__ gin, const unsigned short* __restrict__ W,
    const float* __restrict__ bias, const float* __restrict__ stats, int scOff, int shOff,
    const unsigned short* __restrict__ val, float* __restrict__ outp)
{
  __shared__ __align__(16) unsigned short sA[128*128];
  __shared__ __align__(16) unsigned short sV[128*128];
  int tid=threadIdx.x;
  size_t row0=(size_t)blockIdx.x*128;
  for (int t=tid;t<2048;t+=256){
    int row=t>>4,c=t&15;
    union { uint4 u; unsigned short s[8]; } iv, ov;
    iv.u = *(const uint4*)(gin + (row0+row)*128 + c*8);
    #pragma unroll
    for (int u=0;u<8;u++){
      int ch=c*8+u;
      float x = b2f(iv.s[u]);
      x = gelu_f(fmaf(x, stats[scOff+ch], stats[shOff+ch]));
      ov.s[u]=f2b(x);
    }
    *(uint4*)((char*)sA + swz(row,c*16)) = ov.u;
    uint4 vv = *(const uint4*)(val + (row0+row)*128 + c*8);
    *(uint4*)((char*)sV + swz(row,c*16)) = vv;
  }
  __syncthreads();
  int wid=tid>>6, lane=tid&63;
  int r=lane&15, g=lane>>4;
  f32x4 acc[2][8] = {};
  gemm32(acc, sA, W, wid*32, lane);
  #pragma unroll
  for (int nt=0;nt<8;++nt){
    int ch=nt*16+r; float bc=bias[ch];
    #pragma unroll
    for (int mt=0;mt<2;++mt){
      float g3[4], vv[4];
      #pragma unroll
      for (int rr=0;rr<4;++rr){
        int row=wid*32+mt*16+g*4+rr;
        g3[rr]=acc[mt][nt][rr]+bc;
        vv[rr]=b2f(*(const unsigned short*)((const char*)sV + swz(row, ch*2)));
      }
      float m = fmaxf(fmaxf(g3[0],g3[1]),fmaxf(g3[2],g3[3]));
      m = fmaxf(m, __shfl_xor(m,16));
      m = fmaxf(m, __shfl_xor(m,32));
      float s=0.f, o=0.f;
      #pragma unroll
      for (int rr=0;rr<4;++rr){
        float e = __expf(g3[rr]-m);
        s += e; o = fmaf(e, vv[rr], o);
      }
      s += __shfl_xor(s,16); s += __shfl_xor(s,32);
      o += __shfl_xor(o,16); o += __shfl_xor(o,32);
      if (g==0){
        int p = wid*2+mt;
        outp[((size_t)blockIdx.x*8 + p)*128 + ch] = o/s;
      }
    }
  }
}

extern "C" void kernel_launch(void* const* d_in, const int* in_sizes, int n_in,
                              void* d_out, int out_size, void* d_ws, size_t ws_size,
                              hipStream_t stream)
{
  const float* feats  = (const float*)d_in[0];
  const float* points = (const float*)d_in[1];
  const float* Wq = (const float*)d_in[2];  const float* bq = (const float*)d_in[3];
  const float* Wk = (const float*)d_in[4];  const float* bk = (const float*)d_in[5];
  const float* Wv = (const float*)d_in[6];  const float* bv = (const float*)d_in[7];
  const float* Wd1= (const float*)d_in[8];  const float* bd1= (const float*)d_in[9];
  const float* Wd2= (const float*)d_in[10]; const float* bd2= (const float*)d_in[11];
  const float* Wg1= (const float*)d_in[12]; const float* bg1= (const float*)d_in[13];
  const float* Wg2= (const float*)d_in[14]; const float* bg2= (const float*)d_in[15];
  const float* gd = (const float*)d_in[16]; const float* betad = (const float*)d_in[17];
  const float* gg1= (const float*)d_in[18]; const float* betag1= (const float*)d_in[19];
  const float* gg2= (const float*)d_in[20]; const float* betag2= (const float*)d_in[21];
  float* outp = (float*)d_out;

  char* ws = (char*)d_ws;
  int*    idxb  = (int*)   (ws + 0);                         // 1 MB
  float*  stats = (float*) (ws + 1048576);                   // ~68 KB
  unsigned short* wbf   = (unsigned short*)(ws + 1179648);   // 160 KB
  unsigned short* featb = (unsigned short*)(ws + 1343488);   // 4 MB
  unsigned short* kb    = (unsigned short*)(ws + 5537792);   // 4 MB
  unsigned short* vbuf  = (unsigned short*)(ws + 9732096);   // 4 MB
  unsigned short* g1b = (unsigned short*)(ws + 13926400);    // 64 MB
  unsigned short* vab = (unsigned short*)(ws + 81035264);    // 64 MB
  unsigned short* g2b = (unsigned short*)(ws + 148144128);   // 64 MB
  float*  qbuf  = (float*) (ws + 215252992);                 // 8 MB (ends 223.45MB, within R1-proven 223.5MB)

  k_prep<<<dim3(8192),dim3(256),0,stream>>>(feats,Wq,Wk,Wv,Wg1,Wg2,wbf,featb,stats);
  k_knn4<<<dim3(1024),dim3(256),0,stream>>>(points,idxb);
  k_dstats<<<dim3(64),dim3(256),0,stream>>>(idxb,points,Wd1,bd1,stats);
  k_finalize<<<dim3(1),dim3(64),0,stream>>>(stats,SD_SUM,SD_SSQ,gd,betad,SD_SC,SD_SH,3);
  k_qkv<<<dim3(256),dim3(256),0,stream>>>(featb,wbf,bq,bk,bv,qbuf,kb,vbuf);
  k_fuse<<<dim3(2048),dim3(256),0,stream>>>(points,idxb,qbuf,kb,vbuf,Wd1,bd1,Wd2,bd2,stats,g1b,vab);
  k_finalizeP<<<dim3(2),dim3(64),0,stream>>>(stats,PG1,gg1,betag1,SG1_SC,SG1_SH);
  k_g<<<dim3(2048),dim3(256),0,stream>>>(g1b,wbf+49152,bg1,stats,SG1_SC,SG1_SH,g2b,PG2);
  k_finalizeP<<<dim3(2),dim3(64),0,stream>>>(stats,PG2,gg2,betag2,SG2_SC,SG2_SH);
  k_out<<<dim3(2048),dim3(256),0,stream>>>(g2b,wbf+65536,bg2,stats,SG2_SC,SG2_SH,vab,outp);
  (void)in_sizes; (void)n_in; (void)out_size; (void)ws_size;
}

// Round 10
// 376.527 us; speedup vs baseline: 1.6061x; 1.1791x over previous
//
#include <hip/hip_runtime.h>
#include <hip/hip_bf16.h>
#include <math.h>

#define NPTS 8192
#define STAT_CNT 262144.0f
#define BN_EPS 1e-5f

typedef __attribute__((__ext_vector_type__(8))) __bf16 bf16x8;
typedef __attribute__((__ext_vector_type__(4))) float f32x4;

// stats region float offsets
#define SD_SUM 0
#define SD_SSQ 4
#define SD_SC 8
#define SD_SH 12
#define SG1_SC 16
#define SG1_SH 144
#define SG2_SC 272
#define SG2_SH 400
#define PG1 528
#define PG2 8720
#define STATS_FLOATS 16912

__device__ __forceinline__ unsigned short f2b(float x){
  unsigned u = __float_as_uint(x);
  return (unsigned short)((u + 0x7FFFu + ((u>>16)&1u)) >> 16);
}
__device__ __forceinline__ float b2f(unsigned short h){
  return __uint_as_float(((unsigned)h)<<16);
}
__device__ __forceinline__ float gelu_f(float x){
  return 0.5f*x*(1.0f + erff(x*0.70710678118654752440f));
}
// XOR-swizzled LDS addressing for [rows][256B] bf16 tiles (G4 fix)
__device__ __forceinline__ int swz(int row, int byteInRow){
  return row*256 + (byteInRow ^ ((row&7)<<4));
}
// distance formula shared by both kNN phases: MUST be one inline so phase-1
// and phase-2 roundings are bit-identical (d <= t is exact multiset membership)
__device__ __forceinline__ float dist2f(float qx,float qy,float qz,float qpn,
                                        float x,float y,float z,float w){
  return (qpn + w) - 2.0f*fmaf(qx,x,fmaf(qy,y,qz*z));
}

#define MFMA16(a,b,c) __builtin_amdgcn_mfma_f32_16x16x32_bf16((a),(b),(c),0,0,0)

__device__ __forceinline__ bf16x8 ldsA8(const unsigned short* sA, int row, int k){
  return *(const bf16x8*)((const char*)sA + swz(row, k*2));
}
__device__ __forceinline__ bf16x8 ldW8(const unsigned short* W, int n, int k){
  return *(const bf16x8*)(W + n*128 + k);
}

// wave computes rows [row0,row0+32) x 128 cols; A in swizzled LDS, W bf16 [128][128] row-major
__device__ __forceinline__ void gemm32(f32x4 acc[2][8], const unsigned short* sA,
                                       const unsigned short* W, int row0, int lane){
  int r = lane & 15, g = lane >> 4;
  #pragma unroll
  for (int ks=0; ks<4; ++ks){
    int k = ks*32 + g*8;
    bf16x8 a0 = ldsA8(sA, row0 + r, k);
    bf16x8 a1 = ldsA8(sA, row0 + 16 + r, k);
    #pragma unroll
    for (int nt=0; nt<8; ++nt){
      bf16x8 b = ldW8(W, nt*16 + r, k);
      acc[0][nt] = MFMA16(a0, b, acc[0][nt]);
      acc[1][nt] = MFMA16(a1, b, acc[1][nt]);
    }
  }
}

__global__ __launch_bounds__(256) void k_prep(
    const float* __restrict__ feats, const float* __restrict__ Wq, const float* __restrict__ Wk,
    const float* __restrict__ Wv, const float* __restrict__ Wg1, const float* __restrict__ Wg2,
    unsigned short* __restrict__ wbf, unsigned short* __restrict__ featb, float* __restrict__ stats)
{
  int i = blockIdx.x*256 + threadIdx.x;   // grid covers exactly 2097152
  featb[i] = f2b(feats[i]);
  if (i < 16384){
    wbf[i]        = f2b(Wq[i]);
    wbf[16384+i]  = f2b(Wk[i]);
    wbf[32768+i]  = f2b(Wv[i]);
    wbf[49152+i]  = f2b(Wg1[i]);
    wbf[65536+i]  = f2b(Wg2[i]);
  }
  if (i < STATS_FLOATS) stats[i] = 0.f;
}

// barrier-free threshold-filter kNN, 4 queries/wave, candidates read DIRECTLY
// from global (96KB/batch = L2-resident; R9 lesson: LDS staging + barriers
// serialized waves at 3 blocks/CU). Survivor buffers are wave-private -> no
// inter-wave sync. Selection = rank-by-count over ~18 survivors (no removal
// step; ranks unique under strict lex-(d,idx) order).
__global__ __launch_bounds__(256) void k_knn5(const float* __restrict__ points, int* __restrict__ idxb){
  __shared__ float svD[16][64];
  __shared__ int   svI[16][64];
  __shared__ int   svC[16];
  int tid = threadIdx.x;
  int wid = tid>>6, lane = tid&63;
  int blk = blockIdx.x;
  int b = (blk*16) >> 13;           // 16 divides 8192: no batch straddle
  const float* cb = points + (size_t)b*NPTS*3;
  int qbase = blk*16 + wid*4;
  float qx[4],qy[4],qz[4],qpn[4],lmin[4],tq[4];
  #pragma unroll
  for (int q=0;q<4;++q){
    const float* qp = points + (size_t)(qbase+q)*3;
    qx[q]=qp[0]; qy[q]=qp[1]; qz[q]=qp[2];
    qpn[q]=fmaf(qz[q],qz[q],fmaf(qy[q],qy[q],qx[q]*qx[q]));
    lmin[q]=3.4e38f;
  }
  if (lane < 4) svC[wid*4+lane] = 0;   // own wave's counters only
  // ---- phase 1: per-query lane minima over lane-strided candidates ----
  #pragma unroll 4
  for (int s=0;s<128;++s){
    int p = s*64 + lane;
    const float* sp = cb + (size_t)p*3;
    float x=sp[0], y=sp[1], z=sp[2];
    float w = fmaf(z,z,fmaf(y,y,x*x));
    #pragma unroll
    for (int q=0;q<4;++q){
      float d = dist2f(qx[q],qy[q],qz[q],qpn[q], x,y,z,w);
      lmin[q] = fminf(lmin[q], d);
    }
  }
  // bitonic sort of 64 lane minima per query; t = 16th smallest
  // (16 lanes have min <= t, each contributing >= 1 candidate <= t => d16 <= t)
  #pragma unroll
  for (int q=0;q<4;++q){
    float v = lmin[q];
    #pragma unroll
    for (int k=2;k<=64;k<<=1){
      #pragma unroll
      for (int j=k>>1;j>=1;j>>=1){
        float o = __shfl_xor(v, j);
        bool keepmin = ((lane & j)==0) == ((lane & k)==0);
        v = keepmin ? fminf(v,o) : fmaxf(v,o);
      }
    }
    tq[q] = __shfl(v, 15);
  }
  // ---- phase 2: collect survivors d <= t (E[~18], 64 slots) ----
  #pragma unroll 2
  for (int s=0;s<128;++s){
    int p = s*64 + lane;
    const float* sp = cb + (size_t)p*3;
    float x=sp[0], y=sp[1], z=sp[2];
    float w = fmaf(z,z,fmaf(y,y,x*x));
    #pragma unroll
    for (int q=0;q<4;++q){
      float d = dist2f(qx[q],qy[q],qz[q],qpn[q], x,y,z,w);
      if (d <= tq[q]){
        int wq = wid*4+q;
        int slot = atomicAdd(&svC[wq], 1);
        if (slot < 64){ svD[wq][slot]=d; svI[wq][slot]=p; }
      }
    }
  }
  __syncthreads();   // insurance only (buffers are wave-private)
  // ---- final: rank-by-count selection per query ----
  #pragma unroll 1
  for (int q=0;q<4;++q){
    int wq = wid*4+q;
    int n = svC[wq]; n = (n>64)?64:n;   // n >= 16 guaranteed
    float d = (lane<n)? svD[wq][lane] : 3.4e38f;
    int   ii = (lane<n)? svI[wq][lane] : 0x7fffffff;
    int rank = 0;
    #pragma unroll 4
    for (int j=0;j<n;++j){              // broadcast LDS reads, conflict-free
      float od = svD[wq][j]; int oi = svI[wq][j];
      rank += ((od<d)||(od==d && oi<ii)) ? 1 : 0;
    }
    if (lane<n && rank<16) idxb[(size_t)(qbase+q)*16 + rank] = ii;
  }
}

// thread-per-query BN-d statistics over pos1 = Wd1*(q - nbr) + bd1
__global__ __launch_bounds__(256) void k_dstats(const int* __restrict__ idxb,
    const float* __restrict__ points, const float* __restrict__ Wd1, const float* __restrict__ bd1,
    float* __restrict__ stats){
  __shared__ float sS[6];
  if (threadIdx.x < 6) sS[threadIdx.x]=0.f;
  __syncthreads();
  int qi = blockIdx.x*256 + threadIdx.x;
  int b = qi >> 13;
  const float* qp = points + (size_t)qi*3;
  float qx=qp[0],qy=qp[1],qz=qp[2];
  float w00=Wd1[0],w01=Wd1[1],w02=Wd1[2],w10=Wd1[3],w11=Wd1[4],w12=Wd1[5],w20=Wd1[6],w21=Wd1[7],w22=Wd1[8];
  float b0=bd1[0],b1=bd1[1],b2=bd1[2];
  float s0=0,s1=0,s2=0,q0=0,q1=0,q2=0;
  #pragma unroll
  for (int j=0;j<16;j++){
    int nb = idxb[(size_t)qi*16 + j];
    const float* np_ = points + (size_t)(b*NPTS + nb)*3;
    float dx=qx-np_[0], dy=qy-np_[1], dz=qz-np_[2];
    float t0 = fmaf(dz,w02,fmaf(dy,w01,dx*w00)) + b0;
    float t1 = fmaf(dz,w12,fmaf(dy,w11,dx*w10)) + b1;
    float t2 = fmaf(dz,w22,fmaf(dy,w21,dx*w20)) + b2;
    s0+=t0; s1+=t1; s2+=t2;
    q0=fmaf(t0,t0,q0); q1=fmaf(t1,t1,q1); q2=fmaf(t2,t2,q2);
  }
  atomicAdd(&sS[0],s0); atomicAdd(&sS[1],s1); atomicAdd(&sS[2],s2);
  atomicAdd(&sS[3],q0); atomicAdd(&sS[4],q1); atomicAdd(&sS[5],q2);
  __syncthreads();
  if (threadIdx.x < 3) atomicAdd(&stats[SD_SUM+threadIdx.x], sS[threadIdx.x]);
  else if (threadIdx.x < 6) atomicAdd(&stats[SD_SSQ+threadIdx.x-3], sS[threadIdx.x]);
}

__global__ void k_finalize(float* stats, int sumOff, int ssqOff, const float* __restrict__ gm,
                           const float* __restrict__ bt, int scOff, int shOff, int C){
  int c = blockIdx.x*64 + threadIdx.x;
  if (c >= C) return;
  float m = stats[sumOff+c] * (1.0f/STAT_CNT);
  float v = stats[ssqOff+c] * (1.0f/STAT_CNT) - m*m;
  v = fmaxf(v, 0.0f);
  float rs = rsqrtf(v + BN_EPS);
  float sc = gm[c]*rs;
  stats[scOff+c] = sc;
  stats[shOff+c] = fmaf(-m, sc, bt[c]);
}

// finalize from 32 partial slots of [sum128, ssq128]
__global__ void k_finalizeP(float* stats, int partOff, const float* __restrict__ gm,
                            const float* __restrict__ bt, int scOff, int shOff){
  int c = blockIdx.x*64 + threadIdx.x;   // 2 blocks x 64
  float s=0.f, q=0.f;
  #pragma unroll 4
  for (int p=0;p<32;p++){
    s += stats[partOff + p*256 + c];
    q += stats[partOff + p*256 + 128 + c];
  }
  float m = s * (1.0f/STAT_CNT);
  float v = fmaxf(q*(1.0f/STAT_CNT) - m*m, 0.0f);
  float rs = rsqrtf(v + BN_EPS);
  float sc = gm[c]*rs;
  stats[scOff+c] = sc;
  stats[shOff+c] = fmaf(-m, sc, bt[c]);
}

// fused Q/K/V projection over contiguous feature rows: 64 rows/block, 4 waves.
// Q stored fp32 (qbuf); K,V stored bf16 with bias folded (kb, vb).
__global__ __launch_bounds__(256) void k_qkv(
    const unsigned short* __restrict__ featb, const unsigned short* __restrict__ wbf,
    const float* __restrict__ bq, const float* __restrict__ bk, const float* __restrict__ bv,
    float* __restrict__ qout, unsigned short* __restrict__ kout, unsigned short* __restrict__ vout)
{
  __shared__ __align__(16) unsigned short sA[64*128];
  int tid = threadIdx.x;
  size_t row0g = (size_t)blockIdx.x*64;
  for (int t=tid; t<1024; t+=256){
    int row=t>>4, cc=t&15;
    uint4 v = *(const uint4*)(featb + (row0g+row)*128 + cc*8);
    *(uint4*)((char*)sA + swz(row, cc*16)) = v;
  }
  __syncthreads();
  int wid=tid>>6, lane=tid&63;
  int r=lane&15, g=lane>>4;
  int row0 = wid*16;
  f32x4 aQ[8]={}, aK[8]={}, aV[8]={};
  const unsigned short* WQ = wbf;
  const unsigned short* WK = wbf+16384;
  const unsigned short* WV = wbf+32768;
  #pragma unroll
  for (int ks=0;ks<4;++ks){
    int k = ks*32 + g*8;
    bf16x8 a0 = ldsA8(sA, row0+r, k);
    #pragma unroll
    for (int nt=0;nt<8;++nt){
      aQ[nt]=MFMA16(a0, ldW8(WQ,nt*16+r,k), aQ[nt]);
      aK[nt]=MFMA16(a0, ldW8(WK,nt*16+r,k), aK[nt]);
      aV[nt]=MFMA16(a0, ldW8(WV,nt*16+r,k), aV[nt]);
    }
  }
  #pragma unroll
  for (int nt=0;nt<8;++nt){
    int ch=nt*16+r;
    float bqc=bq[ch], bkc=bk[ch], bvc=bv[ch];
    #pragma unroll
    for (int rr=0;rr<4;++rr){
      size_t grow = row0g + row0 + g*4 + rr;
      qout[grow*128+ch] = aQ[nt][rr]+bqc;
      kout[grow*128+ch] = f2b(aK[nt][rr]+bkc);
      vout[grow*128+ch] = f2b(aV[nt][rr]+bvc);
    }
  }
}

// streaming fusion: gamma1 = q - gather(K) + pos ; val = gather(V) + pos.
// No GEMM, no LDS tile, no in-loop barriers (R8 lesson: k_main's phase-chain
// was latency-doomed at 2 blocks/CU). 16-lane group per gamma row; 8 ch/thread.
__global__ __launch_bounds__(256) void k_fuse(
    const float* __restrict__ points, const int* __restrict__ idxb,
    const float* __restrict__ qbuf, const unsigned short* __restrict__ kb,
    const unsigned short* __restrict__ vb,
    const float* __restrict__ Wd1, const float* __restrict__ bd1,
    const float* __restrict__ Wd2, const float* __restrict__ bd2,
    float* __restrict__ stats,
    unsigned short* __restrict__ g1out, unsigned short* __restrict__ valout)
{
  __shared__ float sSum[128];
  __shared__ float sSq[128];
  int tid = threadIdx.x, blk = blockIdx.x;
  int slot = tid & 15, jg = tid >> 4;
  int lane = tid & 63;
  int ch0 = slot*8;
  if (tid < 128){ sSum[tid]=0.f; sSq[tid]=0.f; }
  // hoisted per-thread weights (static-indexed arrays -> registers)
  float w2[24], b2v[8];
  #pragma unroll
  for (int u=0;u<8;++u){
    w2[u*3+0]=Wd2[(ch0+u)*3+0];
    w2[u*3+1]=Wd2[(ch0+u)*3+1];
    w2[u*3+2]=Wd2[(ch0+u)*3+2];
    b2v[u]=bd2[ch0+u];
  }
  // this lane computes pos1 component c (lanes 0..2 of each 16-group are read)
  int c = slot & 3; c = (c==3)?2:c;
  float wa  = (c==0)?Wd1[0]:((c==1)?Wd1[3]:Wd1[6]);
  float wb_ = (c==0)?Wd1[1]:((c==1)?Wd1[4]:Wd1[7]);
  float wc  = (c==0)?Wd1[2]:((c==1)?Wd1[5]:Wd1[8]);
  float bc_ = (c==0)?bd1[0]:((c==1)?bd1[1]:bd1[2]);
  float sc_ = (c==0)?stats[SD_SC+0]:((c==1)?stats[SD_SC+1]:stats[SD_SC+2]);
  float sh_ = (c==0)?stats[SD_SH+0]:((c==1)?stats[SD_SH+1]:stats[SD_SH+2]);
  int base = lane & 48;
  float accS[8]={0,0,0,0,0,0,0,0}, accQ[8]={0,0,0,0,0,0,0,0};
  __syncthreads();
  #pragma unroll 2
  for (int i=0;i<8;++i){
    int q = blk*8 + i;
    int b = q >> 13;
    int row = q*16 + jg;
    int nb = idxb[row];
    const float* ctr = points + (size_t)q*3;
    const float* np_ = points + (size_t)(b*NPTS + nb)*3;
    float dx = ctr[0]-np_[0], dy = ctr[1]-np_[1], dz = ctr[2]-np_[2];
    float t = fmaf(dz, wc, fmaf(dy, wb_, dx*wa)) + bc_;
    float tc = gelu_f(fmaf(t, sc_, sh_));
    float g0  = __shfl(tc, base+0);
    float g1v = __shfl(tc, base+1);
    float g2v = __shfl(tc, base+2);
    size_t kvoff = ((size_t)(b*NPTS + nb))*128 + ch0;
    union { uint4 u; unsigned short s[8]; } K, V, G, Vo;
    K.u = *(const uint4*)(kb + kvoff);
    V.u = *(const uint4*)(vb + kvoff);
    float4 q0 = *(const float4*)(qbuf + (size_t)q*128 + ch0);
    float4 q1 = *(const float4*)(qbuf + (size_t)q*128 + ch0 + 4);
    float qv[8] = {q0.x,q0.y,q0.z,q0.w,q1.x,q1.y,q1.z,q1.w};
    #pragma unroll
    for (int u=0;u<8;++u){
      float pos = fmaf(g2v, w2[u*3+2], fmaf(g1v, w2[u*3+1], g0*w2[u*3+0])) + b2v[u];
      float key = b2f(K.s[u]);
      float val = b2f(V.s[u]) + pos;
      float gmv = qv[u] - key + pos;
      accS[u] += gmv; accQ[u] = fmaf(gmv,gmv,accQ[u]);
      G.s[u] = f2b(gmv); Vo.s[u] = f2b(val);
    }
    *(uint4*)(g1out + (size_t)row*128 + ch0) = G.u;
    *(uint4*)(valout + (size_t)row*128 + ch0) = Vo.u;
  }
  #pragma unroll
  for (int u=0;u<8;++u){
    atomicAdd(&sSum[ch0+u], accS[u]);
    atomicAdd(&sSq[ch0+u], accQ[u]);
  }
  __syncthreads();
  if (tid < 128){
    int ps = blk & 31;
    atomicAdd(&stats[PG1 + ps*256 + tid], sSum[tid]);
    atomicAdd(&stats[PG1 + ps*256 + 128 + tid], sSq[tid]);
  }
}

__global__ __launch_bounds__(256) void k_g(
    const unsigned short* __restrict__ gin, const unsigned short* __restrict__ W,
    const float* __restrict__ bias, float* __restrict__ stats, int scOff, int shOff,
    unsigned short* __restrict__ gout, int partOff)
{
  __shared__ __align__(16) unsigned short sA[128*128];
  __shared__ float sSum[128];
  __shared__ float sSq[128];
  int tid = threadIdx.x;
  size_t row0 = (size_t)blockIdx.x*128;
  if (tid<128){ sSum[tid]=0.f; sSq[tid]=0.f; }
  for (int t=tid; t<2048; t+=256){
    int row=t>>4, c=t&15;
    union { uint4 u; unsigned short s[8]; } iv, ov;
    iv.u = *(const uint4*)(gin + (row0+row)*128 + c*8);
    #pragma unroll
    for (int u=0;u<8;u++){
      int ch = c*8+u;
      float x = b2f(iv.s[u]);
      x = gelu_f(fmaf(x, stats[scOff+ch], stats[shOff+ch]));
      ov.s[u] = f2b(x);
    }
    *(uint4*)((char*)sA + swz(row, c*16)) = ov.u;
  }
  __syncthreads();
  int wid=tid>>6, lane=tid&63;
  int r=lane&15, g=lane>>4;
  f32x4 acc[2][8] = {};
  gemm32(acc, sA, W, wid*32, lane);
  #pragma unroll
  for (int nt=0;nt<8;++nt){
    int ch = nt*16+r;
    float bc = bias[ch];
    float s_=0.f, qq=0.f;
    #pragma unroll
    for (int mt=0;mt<2;++mt){
      #pragma unroll
      for (int rr=0;rr<4;++rr){
        int row = wid*32 + mt*16 + g*4 + rr;
        float x = acc[mt][nt][rr] + bc;
        s_ += x; qq = fmaf(x,x,qq);
        gout[(row0+row)*128 + ch] = f2b(x);
      }
    }
    atomicAdd(&sSum[ch], s_); atomicAdd(&sSq[ch], qq);
  }
  __syncthreads();
  if (tid<128){
    int slot = blockIdx.x & 31;
    atomicAdd(&stats[partOff + slot*256 + tid], sSum[tid]);
    atomicAdd(&stats[partOff + slot*256 + 128 + tid], sSq[tid]);
  }
}

__global__ __launch_bounds__(256) void k_out(
    const unsigned short* __restrict__ gin, const unsigned short* __restrict__ W,
    const float* __restrict__ bias, const float* __restrict__ stats, int scOff, int shOff,
    const unsigned short* __restrict__ val, float* __restrict__ outp)
{
  __shared__ __align__(16) unsigned short sA[128*128];
  __shared__ __align__(16) unsigned short sV[128*128];
  int tid=threadIdx.x;
  size_t row0=(size_t)blockIdx.x*128;
  for (int t=tid;t<2048;t+=256){
    int row=t>>4,c=t&15;
    union { uint4 u; unsigned short s[8]; } iv, ov;
    iv.u = *(const uint4*)(gin + (row0+row)*128 + c*8);
    #pragma unroll
    for (int u=0;u<8;u++){
      int ch=c*8+u;
      float x = b2f(iv.s[u]);
      x = gelu_f(fmaf(x, stats[scOff+ch], stats[shOff+ch]));
      ov.s[u]=f2b(x);
    }
    *(uint4*)((char*)sA + swz(row,c*16)) = ov.u;
    uint4 vv = *(const uint4*)(val + (row0+row)*128 + c*8);
    *(uint4*)((char*)sV + swz(row,c*16)) = vv;
  }
  __syncthreads();
  int wid=tid>>6, lane=tid&63;
  int r=lane&15, g=lane>>4;
  f32x4 acc[2][8] = {};
  gemm32(acc, sA, W, wid*32, lane);
  #pragma unroll
  for (int nt=0;nt<8;++nt){
    int ch=nt*16+r; float bc=bias[ch];
    #pragma unroll
    for (int mt=0;mt<2;++mt){
      float g3[4], vv[4];
      #pragma unroll
      for (int rr=0;rr<4;++rr){
        int row=wid*32+mt*16+g*4+rr;
        g3[rr]=acc[mt][nt][rr]+bc;
        vv[rr]=b2f(*(const unsigned short*)((const char*)sV + swz(row, ch*2)));
      }
      float m = fmaxf(fmaxf(g3[0],g3[1]),fmaxf(g3[2],g3[3]));
      m = fmaxf(m, __shfl_xor(m,16));
      m = fmaxf(m, __shfl_xor(m,32));
      float s=0.f, o=0.f;
      #pragma unroll
      for (int rr=0;rr<4;++rr){
        float e = __expf(g3[rr]-m);
        s += e; o = fmaf(e, vv[rr], o);
      }
      s += __shfl_xor(s,16); s += __shfl_xor(s,32);
      o += __shfl_xor(o,16); o += __shfl_xor(o,32);
      if (g==0){
        int p = wid*2+mt;
        outp[((size_t)blockIdx.x*8 + p)*128 + ch] = o/s;
      }
    }
  }
}

extern "C" void kernel_launch(void* const* d_in, const int* in_sizes, int n_in,
                              void* d_out, int out_size, void* d_ws, size_t ws_size,
                              hipStream_t stream)
{
  const float* feats  = (const float*)d_in[0];
  const float* points = (const float*)d_in[1];
  const float* Wq = (const float*)d_in[2];  const float* bq = (const float*)d_in[3];
  const float* Wk = (const float*)d_in[4];  const float* bk = (const float*)d_in[5];
  const float* Wv = (const float*)d_in[6];  const float* bv = (const float*)d_in[7];
  const float* Wd1= (const float*)d_in[8];  const float* bd1= (const float*)d_in[9];
  const float* Wd2= (const float*)d_in[10]; const float* bd2= (const float*)d_in[11];
  const float* Wg1= (const float*)d_in[12]; const float* bg1= (const float*)d_in[13];
  const float* Wg2= (const float*)d_in[14]; const float* bg2= (const float*)d_in[15];
  const float* gd = (const float*)d_in[16]; const float* betad = (const float*)d_in[17];
  const float* gg1= (const float*)d_in[18]; const float* betag1= (const float*)d_in[19];
  const float* gg2= (const float*)d_in[20]; const float* betag2= (const float*)d_in[21];
  float* outp = (float*)d_out;

  char* ws = (char*)d_ws;
  int*    idxb  = (int*)   (ws + 0);                         // 1 MB
  float*  stats = (float*) (ws + 1048576);                   // ~68 KB
  unsigned short* wbf   = (unsigned short*)(ws + 1179648);   // 160 KB
  unsigned short* featb = (unsigned short*)(ws + 1343488);   // 4 MB
  unsigned short* kb    = (unsigned short*)(ws + 5537792);   // 4 MB
  unsigned short* vbuf  = (unsigned short*)(ws + 9732096);   // 4 MB
  unsigned short* g1b = (unsigned short*)(ws + 13926400);    // 64 MB
  unsigned short* vab = (unsigned short*)(ws + 81035264);    // 64 MB
  unsigned short* g2b = (unsigned short*)(ws + 148144128);   // 64 MB
  float*  qbuf  = (float*) (ws + 215252992);                 // 8 MB (ends 223.45MB, within R1-proven 223.5MB)

  k_prep<<<dim3(8192),dim3(256),0,stream>>>(feats,Wq,Wk,Wv,Wg1,Wg2,wbf,featb,stats);
  k_knn5<<<dim3(1024),dim3(256),0,stream>>>(points,idxb);
  k_dstats<<<dim3(64),dim3(256),0,stream>>>(idxb,points,Wd1,bd1,stats);
  k_finalize<<<dim3(1),dim3(64),0,stream>>>(stats,SD_SUM,SD_SSQ,gd,betad,SD_SC,SD_SH,3);
  k_qkv<<<dim3(256),dim3(256),0,stream>>>(featb,wbf,bq,bk,bv,qbuf,kb,vbuf);
  k_fuse<<<dim3(2048),dim3(256),0,stream>>>(points,idxb,qbuf,kb,vbuf,Wd1,bd1,Wd2,bd2,stats,g1b,vab);
  k_finalizeP<<<dim3(2),dim3(64),0,stream>>>(stats,PG1,gg1,betag1,SG1_SC,SG1_SH);
  k_g<<<dim3(2048),dim3(256),0,stream>>>(g1b,wbf+49152,bg1,stats,SG1_SC,SG1_SH,g2b,PG2);
  k_finalizeP<<<dim3(2),dim3(64),0,stream>>>(stats,PG2,gg2,betag2,SG2_SC,SG2_SH);
  k_out<<<dim3(2048),dim3(256),0,stream>>>(g2b,wbf+65536,bg2,stats,SG2_SC,SG2_SH,vab,outp);
  (void)in_sizes; (void)n_in; (void)out_size; (void)ws_size;
}